// Round 6
// baseline (152.122 us; speedup 1.0000x reference)
//
#include <hip/hip_runtime.h>

#define NUM_CLASSES 5
#define BATCH 4
#define NPB (64 * 256 * 256)            // voxels per batch = 4,194,304
#define VEC_PER_BATCH (NPB / 4)         // int4 vectors per batch = 1,048,576
#define THREADS 256
#define VECS 16                         // int4 per thread per input (64 voxels)
#define CHUNK 4                         // int4 pairs per pipeline stage (16 voxels)
#define NCHUNK (VECS / CHUNK)           // 4 stages
#define BLOCKS_X (VEC_PER_BATCH / (THREADS * VECS))   // 256 per batch
#define SLOTS 15                        // 5 pred, 5 targ, 5 inter
#define PSTRIDE 16                      // padded per-block partial stride

// d_ws: partial[block][PSTRIDE] uints, block = b*BLOCKS_X + bx. No zero-init
// needed: every slot dice_final_kernel reads is written unconditionally.

__global__ __launch_bounds__(THREADS, 4) void dice_count_kernel(
    const int* __restrict__ pred, const int* __restrict__ targ,
    unsigned int* __restrict__ partial) {
  const int b = blockIdx.y;
  const int4* __restrict__ p4 = (const int4*)(pred + (long long)b * NPB);
  const int4* __restrict__ t4 = (const int4*)(targ + (long long)b * NPB);

  const int base = blockIdx.x * (THREADS * VECS) + threadIdx.x;

  // Packed per-lane counters: class c in bits [6c, 6c+6).
  // acc*[half] sums 2 chunks = 32 voxels -> per-field <= 32 < 63, no overflow.
  unsigned accP[2] = {0, 0}, accT[2] = {0, 0}, accI[2] = {0, 0};

  // Rotating software pipeline: compute cur chunk while nxt chunk's 8 loads
  // are in flight. 64 data VGPRs + overhead ~= 90, fits the 128-VGPR cap so
  // the allocator has no pressure reason to sink the prefetch loads.
  int4 curP[CHUNK], curT[CHUNK], nxtP[CHUNK], nxtT[CHUNK];

#pragma unroll
  for (int k = 0; k < CHUNK; ++k) {
    curP[k] = p4[base + k * THREADS];
    curT[k] = t4[base + k * THREADS];
  }

#define ACC_ELEM(PE, TE)                               \
  {                                                    \
    const unsigned op = 1u << (6u * (unsigned)(PE));   \
    aP += op;                                          \
    aT += 1u << (6u * (unsigned)(TE));                 \
    aI += ((PE) == (TE)) ? op : 0u;                    \
  }

#pragma unroll
  for (int h = 0; h < NCHUNK; ++h) {
    // Prefetch chunk h+1 before touching chunk h's data.
    if (h + 1 < NCHUNK) {
#pragma unroll
      for (int k = 0; k < CHUNK; ++k) {
        const int idx = base + ((h + 1) * CHUNK + k) * THREADS;
        nxtP[k] = p4[idx];
        nxtT[k] = t4[idx];
      }
    }
    unsigned aP = 0, aT = 0, aI = 0;
#pragma unroll
    for (int k = 0; k < CHUNK; ++k) {
      ACC_ELEM(curP[k].x, curT[k].x)
      ACC_ELEM(curP[k].y, curT[k].y)
      ACC_ELEM(curP[k].z, curT[k].z)
      ACC_ELEM(curP[k].w, curT[k].w)
    }
    accP[h >> 1] += aP; accT[h >> 1] += aT; accI[h >> 1] += aI;
    if (h + 1 < NCHUNK) {
#pragma unroll
      for (int k = 0; k < CHUNK; ++k) { curP[k] = nxtP[k]; curT[k] = nxtT[k]; }
    }
  }

  // Unpack 6-bit fields of both halves -> 16-bit pairs (per-field <= 64).
#define UNPACK(A, R01, R23, R4)                                          \
  unsigned R01 = ((A[0] & 63u) + (A[1] & 63u)) |                         \
                 ((((A[0] >> 6) & 63u) + ((A[1] >> 6) & 63u)) << 16);    \
  unsigned R23 = (((A[0] >> 12) & 63u) + ((A[1] >> 12) & 63u)) |         \
                 ((((A[0] >> 18) & 63u) + ((A[1] >> 18) & 63u)) << 16);  \
  unsigned R4 = ((A[0] >> 24) & 63u) + ((A[1] >> 24) & 63u);
  UNPACK(accP, p01, p23, p4r)
  UNPACK(accT, t01, t23, t4r)
  UNPACK(accI, i01, i23, i4r)

  // 64-lane butterfly; 16-bit fields hold <= 64*64 = 4096, no overflow.
#pragma unroll
  for (int off = 32; off >= 1; off >>= 1) {
    p01 += (unsigned)__shfl_xor((int)p01, off);
    p23 += (unsigned)__shfl_xor((int)p23, off);
    p4r += (unsigned)__shfl_xor((int)p4r, off);
    t01 += (unsigned)__shfl_xor((int)t01, off);
    t23 += (unsigned)__shfl_xor((int)t23, off);
    t4r += (unsigned)__shfl_xor((int)t4r, off);
    i01 += (unsigned)__shfl_xor((int)i01, off);
    i23 += (unsigned)__shfl_xor((int)i23, off);
    i4r += (unsigned)__shfl_xor((int)i4r, off);
  }

  __shared__ unsigned int s[SLOTS];
  if (threadIdx.x < SLOTS) s[threadIdx.x] = 0;
  __syncthreads();

  if ((threadIdx.x & 63) == 0) {
    atomicAdd(&s[0], p01 & 0xFFFFu);
    atomicAdd(&s[1], p01 >> 16);
    atomicAdd(&s[2], p23 & 0xFFFFu);
    atomicAdd(&s[3], p23 >> 16);
    atomicAdd(&s[4], p4r);
    atomicAdd(&s[5], t01 & 0xFFFFu);
    atomicAdd(&s[6], t01 >> 16);
    atomicAdd(&s[7], t23 & 0xFFFFu);
    atomicAdd(&s[8], t23 >> 16);
    atomicAdd(&s[9], t4r);
    atomicAdd(&s[10], i01 & 0xFFFFu);
    atomicAdd(&s[11], i01 >> 16);
    atomicAdd(&s[12], i23 & 0xFFFFu);
    atomicAdd(&s[13], i23 >> 16);
    atomicAdd(&s[14], i4r);
  }
  __syncthreads();

  if (threadIdx.x < SLOTS)
    partial[(b * BLOCKS_X + blockIdx.x) * PSTRIDE + threadIdx.x] = s[threadIdx.x];
}

__global__ __launch_bounds__(256) void dice_final_kernel(
    const unsigned int* __restrict__ partial, float* __restrict__ out) {
  // 240 active threads: q = t&3 splits each batch's 256 partials into quarters.
  __shared__ unsigned int red[BATCH * SLOTS][4];
  const int t = threadIdx.x;
  if (t < BATCH * SLOTS * 4) {
    const int q = t & 3;
    const int s = (t >> 2) % SLOTS;
    const int bb = (t >> 2) / SLOTS;
    unsigned int sum = 0;
    for (int j = q * (BLOCKS_X / 4); j < (q + 1) * (BLOCKS_X / 4); ++j)
      sum += partial[(bb * BLOCKS_X + j) * PSTRIDE + s];
    red[(t >> 2)][q] = sum;
  }
  __syncthreads();
  if (t < NUM_CLASSES) {
    float acc = 0.0f;
#pragma unroll
    for (int bb = 0; bb < BATCH; ++bb) {
      const int ip = bb * SLOTS + t;
      const int it = bb * SLOTS + 5 + t;
      const int ii = bb * SLOTS + 10 + t;
      const float ps = (float)(red[ip][0] + red[ip][1] + red[ip][2] + red[ip][3]);
      const float ts = (float)(red[it][0] + red[it][1] + red[it][2] + red[it][3]);
      const float is = (float)(red[ii][0] + red[ii][1] + red[ii][2] + red[ii][3]);
      float num = 2.0f * is;
      float den = ps + ts;
      if (den == 0.0f) { num = 1.0f; den = 1.0f; }
      acc += num / den;
    }
    out[t] = acc * (1.0f / BATCH);
  }
}

extern "C" void kernel_launch(void* const* d_in, const int* in_sizes, int n_in,
                              void* d_out, int out_size, void* d_ws, size_t ws_size,
                              hipStream_t stream) {
  const int* pred = (const int*)d_in[0];
  const int* targ = (const int*)d_in[1];
  float* out = (float*)d_out;
  unsigned int* partial = (unsigned int*)d_ws;

  dim3 grid(BLOCKS_X, BATCH);
  dice_count_kernel<<<grid, THREADS, 0, stream>>>(pred, targ, partial);
  dice_final_kernel<<<1, 256, 0, stream>>>(partial, out);
}

// Round 7
// 150.319 us; speedup vs baseline: 1.0120x; 1.0120x over previous
//
#include <hip/hip_runtime.h>

#define NUM_CLASSES 5
#define BATCH 4
#define NPB (64 * 256 * 256)            // voxels per batch = 4,194,304
#define VEC_PER_BATCH (NPB / 4)         // int4 vectors per batch = 1,048,576
#define THREADS 256
#define VECS 16                         // int4 per thread per input (64 voxels)
#define DEPTH 6                         // pipeline slots (12 loads in flight)
#define BLOCKS_X (VEC_PER_BATCH / (THREADS * VECS))   // 256 per batch
#define SLOTS 15                        // 5 pred, 5 targ, 5 inter
#define PSTRIDE 16                      // padded per-block partial stride

typedef int vint4 __attribute__((ext_vector_type(4)));

// d_ws: partial[block][PSTRIDE] uints, block = b*BLOCKS_X + bx. No zero-init
// needed: every slot dice_final_kernel reads is written unconditionally.

__global__ __launch_bounds__(THREADS, 4) void dice_count_kernel(
    const int* __restrict__ pred, const int* __restrict__ targ,
    unsigned int* __restrict__ partial) {
  const int b = blockIdx.y;
  const vint4* __restrict__ p4 = (const vint4*)(pred + (long long)b * NPB);
  const vint4* __restrict__ t4 = (const vint4*)(targ + (long long)b * NPB);

  const int base = blockIdx.x * (THREADS * VECS) + threadIdx.x;

  // Rotating 6-slot register pipeline, loads issued via inline asm so the
  // compiler can neither sink nor coalesce them. Steady state: 12 dwordx4
  // loads in flight per wave (12 KB/wave). vmcnt accounting: before
  // computing pair j, issued = 12+2j, need first 2(j+1) retired ->
  // wait vmcnt(10) (vmcnt retires oldest-first).
  vint4 pv[DEPTH], tv[DEPTH];

#define ISSUE(J)                                                            \
  {                                                                         \
    const void* ap_ = (const void*)(p4 + base + (J) * THREADS);             \
    const void* at_ = (const void*)(t4 + base + (J) * THREADS);             \
    asm volatile("global_load_dwordx4 %0, %1, off"                          \
                 : "=v"(pv[(J) % DEPTH]) : "v"(ap_) : "memory");            \
    asm volatile("global_load_dwordx4 %0, %1, off"                          \
                 : "=v"(tv[(J) % DEPTH]) : "v"(at_) : "memory");            \
  }

  // WAITP(N, slot): wait until pair in `slot` has landed; tying the quads
  // through the asm makes every consumer data-dependent on the waitcnt.
#define WAITP(N, J)                                                         \
  asm volatile("s_waitcnt vmcnt(" #N ")"                                    \
               : "+v"(pv[(J) % DEPTH]), "+v"(tv[(J) % DEPTH]) :: "memory");

  // Packed per-lane counters: class c in bits [6c, 6c+6).
  // Pairs 0..7 -> index 0, 8..15 -> index 1: <=32 voxels per field, no ovf.
  unsigned accP[2] = {0, 0}, accT[2] = {0, 0}, accI[2] = {0, 0};

#define ACC_ELEM(H, PE, TE)                                                 \
  {                                                                         \
    const unsigned op = 1u << (6u * (unsigned)(PE));                        \
    accP[H] += op;                                                          \
    accT[H] += 1u << (6u * (unsigned)(TE));                                 \
    accI[H] += ((PE) == (TE)) ? op : 0u;                                    \
  }

#define PAIRC(J)                                                            \
  {                                                                         \
    const int hh = ((J) < 8) ? 0 : 1;                                       \
    const vint4 pvv = pv[(J) % DEPTH];                                      \
    const vint4 tvv = tv[(J) % DEPTH];                                      \
    ACC_ELEM(hh, pvv.x, tvv.x)                                              \
    ACC_ELEM(hh, pvv.y, tvv.y)                                              \
    ACC_ELEM(hh, pvv.z, tvv.z)                                              \
    ACC_ELEM(hh, pvv.w, tvv.w)                                              \
  }

#pragma unroll
  for (int j = 0; j < DEPTH; ++j) ISSUE(j)

#pragma unroll
  for (int j = 0; j < VECS - DEPTH; ++j) {   // j = 0..9
    WAITP(10, j)
    PAIRC(j)
    ISSUE(j + DEPTH)
  }
  // Tail drain: outstanding 12, no more issues.
  WAITP(10, 10) PAIRC(10)
  WAITP(8, 11)  PAIRC(11)
  WAITP(6, 12)  PAIRC(12)
  WAITP(4, 13)  PAIRC(13)
  WAITP(2, 14)  PAIRC(14)
  WAITP(0, 15)  PAIRC(15)

  // Unpack 6-bit fields of both halves -> 16-bit pairs (per-field <= 64).
#define UNPACK(A, R01, R23, R4)                                          \
  unsigned R01 = ((A[0] & 63u) + (A[1] & 63u)) |                         \
                 ((((A[0] >> 6) & 63u) + ((A[1] >> 6) & 63u)) << 16);    \
  unsigned R23 = (((A[0] >> 12) & 63u) + ((A[1] >> 12) & 63u)) |         \
                 ((((A[0] >> 18) & 63u) + ((A[1] >> 18) & 63u)) << 16);  \
  unsigned R4 = ((A[0] >> 24) & 63u) + ((A[1] >> 24) & 63u);
  UNPACK(accP, p01, p23, p4r)
  UNPACK(accT, t01, t23, t4r)
  UNPACK(accI, i01, i23, i4r)

  // 64-lane butterfly; 16-bit fields hold <= 64*64 = 4096, no overflow.
#pragma unroll
  for (int off = 32; off >= 1; off >>= 1) {
    p01 += (unsigned)__shfl_xor((int)p01, off);
    p23 += (unsigned)__shfl_xor((int)p23, off);
    p4r += (unsigned)__shfl_xor((int)p4r, off);
    t01 += (unsigned)__shfl_xor((int)t01, off);
    t23 += (unsigned)__shfl_xor((int)t23, off);
    t4r += (unsigned)__shfl_xor((int)t4r, off);
    i01 += (unsigned)__shfl_xor((int)i01, off);
    i23 += (unsigned)__shfl_xor((int)i23, off);
    i4r += (unsigned)__shfl_xor((int)i4r, off);
  }

  __shared__ unsigned int s[SLOTS];
  if (threadIdx.x < SLOTS) s[threadIdx.x] = 0;
  __syncthreads();

  if ((threadIdx.x & 63) == 0) {
    atomicAdd(&s[0], p01 & 0xFFFFu);
    atomicAdd(&s[1], p01 >> 16);
    atomicAdd(&s[2], p23 & 0xFFFFu);
    atomicAdd(&s[3], p23 >> 16);
    atomicAdd(&s[4], p4r);
    atomicAdd(&s[5], t01 & 0xFFFFu);
    atomicAdd(&s[6], t01 >> 16);
    atomicAdd(&s[7], t23 & 0xFFFFu);
    atomicAdd(&s[8], t23 >> 16);
    atomicAdd(&s[9], t4r);
    atomicAdd(&s[10], i01 & 0xFFFFu);
    atomicAdd(&s[11], i01 >> 16);
    atomicAdd(&s[12], i23 & 0xFFFFu);
    atomicAdd(&s[13], i23 >> 16);
    atomicAdd(&s[14], i4r);
  }
  __syncthreads();

  if (threadIdx.x < SLOTS)
    partial[(b * BLOCKS_X + blockIdx.x) * PSTRIDE + threadIdx.x] = s[threadIdx.x];
}

__global__ __launch_bounds__(256) void dice_final_kernel(
    const unsigned int* __restrict__ partial, float* __restrict__ out) {
  // 240 active threads: q = t&3 splits each batch's 256 partials into quarters.
  __shared__ unsigned int red[BATCH * SLOTS][4];
  const int t = threadIdx.x;
  if (t < BATCH * SLOTS * 4) {
    const int q = t & 3;
    const int s = (t >> 2) % SLOTS;
    const int bb = (t >> 2) / SLOTS;
    unsigned int sum = 0;
    for (int j = q * (BLOCKS_X / 4); j < (q + 1) * (BLOCKS_X / 4); ++j)
      sum += partial[(bb * BLOCKS_X + j) * PSTRIDE + s];
    red[(t >> 2)][q] = sum;
  }
  __syncthreads();
  if (t < NUM_CLASSES) {
    float acc = 0.0f;
#pragma unroll
    for (int bb = 0; bb < BATCH; ++bb) {
      const int ip = bb * SLOTS + t;
      const int it = bb * SLOTS + 5 + t;
      const int ii = bb * SLOTS + 10 + t;
      const float ps = (float)(red[ip][0] + red[ip][1] + red[ip][2] + red[ip][3]);
      const float ts = (float)(red[it][0] + red[it][1] + red[it][2] + red[it][3]);
      const float is = (float)(red[ii][0] + red[ii][1] + red[ii][2] + red[ii][3]);
      float num = 2.0f * is;
      float den = ps + ts;
      if (den == 0.0f) { num = 1.0f; den = 1.0f; }
      acc += num / den;
    }
    out[t] = acc * (1.0f / BATCH);
  }
}

extern "C" void kernel_launch(void* const* d_in, const int* in_sizes, int n_in,
                              void* d_out, int out_size, void* d_ws, size_t ws_size,
                              hipStream_t stream) {
  const int* pred = (const int*)d_in[0];
  const int* targ = (const int*)d_in[1];
  float* out = (float*)d_out;
  unsigned int* partial = (unsigned int*)d_ws;

  dim3 grid(BLOCKS_X, BATCH);
  dice_count_kernel<<<grid, THREADS, 0, stream>>>(pred, targ, partial);
  dice_final_kernel<<<1, 256, 0, stream>>>(partial, out);
}